// Round 1
// baseline (353.388 us; speedup 1.0000x reference)
//
#include <hip/hip_runtime.h>
#include <math.h>

#define NB 64
#define NC 512
#define NHW 4096
#define NHID 32

// ---------------- Kernel 1: global average pool ----------------
// One block per (b,c) plane: 4096 floats = 1024 float4; 256 threads x 4 float4.
__global__ __launch_bounds__(256) void pool_kernel(const float* __restrict__ x,
                                                   float* __restrict__ y) {
    const int bc = blockIdx.x;                       // 0 .. NB*NC-1
    const float4* __restrict__ xin =
        reinterpret_cast<const float4*>(x + (size_t)bc * NHW);
    const int tid = threadIdx.x;

    float s = 0.f;
#pragma unroll
    for (int i = 0; i < 4; ++i) {
        float4 v = xin[tid + i * 256];               // coalesced per iteration
        s += v.x + v.y + v.z + v.w;
    }
    // wave(64) shuffle reduce
#pragma unroll
    for (int o = 32; o; o >>= 1) s += __shfl_down(s, o, 64);

    __shared__ float partial[4];
    const int wid = tid >> 6;
    if ((tid & 63) == 0) partial[wid] = s;
    __syncthreads();
    if (tid == 0) {
        float t = partial[0] + partial[1] + partial[2] + partial[3];
        y[bc] = t * (1.0f / NHW);
    }
}

// ---------------- Kernel 2: routed 2-layer MLP -> sigmoid gate ----------------
// One block (256 threads) per sample b.
__global__ __launch_bounds__(256) void gate_kernel(const float* __restrict__ y,
                                                   const int* __restrict__ dataset,
                                                   const float* __restrict__ W1,
                                                   const float* __restrict__ W2,
                                                   float* __restrict__ gate) {
    const int b = blockIdx.x;
    const int tid = threadIdx.x;

    __shared__ float ys[NC];
    __shared__ float hs[NHID];

    ys[tid]       = y[b * NC + tid];
    ys[tid + 256] = y[b * NC + tid + 256];
    const int e = dataset[b];
    __syncthreads();

    // Stage 1: h[hid] = relu( sum_c y[c] * W1[e][hid][c] ), 8 lanes per hid
    const int hid = tid >> 3;                        // 0..31
    const int j   = tid & 7;                         // 0..7
    const float* __restrict__ w1row = W1 + ((size_t)e * NHID + hid) * NC;
    float acc = 0.f;
    for (int c = j; c < NC; c += 8) acc += ys[c] * w1row[c];
#pragma unroll
    for (int o = 4; o; o >>= 1) acc += __shfl_down(acc, o, 8);
    if (j == 0) hs[hid] = fmaxf(acc, 0.f);
    __syncthreads();

    // Stage 2: gate[c] = sigmoid( sum_h hs[h] * W2[e][c][h] ); 2 channels/thread
    const float* __restrict__ w2base = W2 + (size_t)e * NC * NHID;
#pragma unroll
    for (int k = 0; k < 2; ++k) {
        const int c = tid + k * 256;
        const float* __restrict__ w2row = w2base + c * NHID;
        float z = 0.f;
#pragma unroll
        for (int hh = 0; hh < NHID; ++hh) z += hs[hh] * w2row[hh];
        gate[b * NC + c] = 1.0f / (1.0f + expf(-z));
    }
}

// ---------------- Kernel 3: out = x * gate[b,c] ----------------
// Grid-stride float4; 1024 float4 per (b,c) plane -> gate index = i >> 10.
__global__ __launch_bounds__(256) void scale_kernel(const float* __restrict__ x,
                                                    const float* __restrict__ gate,
                                                    float* __restrict__ out) {
    const size_t total4 = (size_t)NB * NC * NHW / 4; // 33,554,432
    const size_t stride = (size_t)gridDim.x * blockDim.x;
    for (size_t i = (size_t)blockIdx.x * 256 + threadIdx.x; i < total4; i += stride) {
        const float g = gate[i >> 10];
        float4 v = reinterpret_cast<const float4*>(x)[i];
        v.x *= g; v.y *= g; v.z *= g; v.w *= g;
        reinterpret_cast<float4*>(out)[i] = v;
    }
}

extern "C" void kernel_launch(void* const* d_in, const int* in_sizes, int n_in,
                              void* d_out, int out_size, void* d_ws, size_t ws_size,
                              hipStream_t stream) {
    const float* x       = (const float*)d_in[0];
    const int*   dataset = (const int*)d_in[1];
    const float* W1      = (const float*)d_in[2];
    const float* W2      = (const float*)d_in[3];
    float* out = (float*)d_out;

    float* y    = (float*)d_ws;          // NB*NC floats
    float* gate = y + NB * NC;           // NB*NC floats

    pool_kernel<<<NB * NC, 256, 0, stream>>>(x, y);
    gate_kernel<<<NB, 256, 0, stream>>>(y, dataset, W1, W2, gate);
    scale_kernel<<<2048, 256, 0, stream>>>(x, gate, out);
}

// Round 2
// 284.909 us; speedup vs baseline: 1.2404x; 1.2404x over previous
//
#include <hip/hip_runtime.h>
#include <math.h>

#define NB 64
#define NC 512
#define NHW 4096
#define NHID 32
#define NPLANES (NB * NC)          // 32768 planes of 4096 floats

typedef float f32x4 __attribute__((ext_vector_type(4)));

// ---------------- Kernel 1: global average pool ----------------
// Wave-per-plane: each 64-lane wave reduces one 16 KiB plane entirely in
// registers (16 float4/lane), 6-shfl butterfly, no LDS, no barrier.
__global__ __launch_bounds__(256) void pool_kernel(const float* __restrict__ x,
                                                   float* __restrict__ y) {
    const int wid   = threadIdx.x >> 6;
    const int lane  = threadIdx.x & 63;
    const int plane = blockIdx.x * 4 + wid;
    const f32x4* __restrict__ xin =
        reinterpret_cast<const f32x4*>(x + (size_t)plane * NHW);

    float s = 0.f;
#pragma unroll
    for (int i = 0; i < 16; ++i) {
        f32x4 v = xin[lane + i * 64];                // 1 KiB contiguous per wave-iter
        s += v.x + v.y + v.z + v.w;
    }
#pragma unroll
    for (int o = 32; o; o >>= 1) s += __shfl_down(s, o, 64);
    if (lane == 0) y[plane] = s * (1.0f / NHW);
}

// ---------------- Kernel 2: routed 2-layer MLP -> sigmoid gate ----------------
// One block (256 threads) per sample b. Tiny (few us).
__global__ __launch_bounds__(256) void gate_kernel(const float* __restrict__ y,
                                                   const int* __restrict__ dataset,
                                                   const float* __restrict__ W1,
                                                   const float* __restrict__ W2,
                                                   float* __restrict__ gate) {
    const int b = blockIdx.x;
    const int tid = threadIdx.x;

    __shared__ float ys[NC];
    __shared__ float hs[NHID];

    ys[tid]       = y[b * NC + tid];
    ys[tid + 256] = y[b * NC + tid + 256];
    const int e = dataset[b];
    __syncthreads();

    // Stage 1: h[hid] = relu( sum_c y[c] * W1[e][hid][c] ), 8 lanes per hid
    const int hid = tid >> 3;
    const int j   = tid & 7;
    const float* __restrict__ w1row = W1 + ((size_t)e * NHID + hid) * NC;
    float acc = 0.f;
    for (int c = j; c < NC; c += 8) acc += ys[c] * w1row[c];
#pragma unroll
    for (int o = 4; o; o >>= 1) acc += __shfl_down(acc, o, 8);
    if (j == 0) hs[hid] = fmaxf(acc, 0.f);
    __syncthreads();

    // Stage 2: gate[c] = sigmoid( sum_h hs[h] * W2[e][c][h] ); 2 channels/thread
    const float* __restrict__ w2base = W2 + (size_t)e * NC * NHID;
#pragma unroll
    for (int k = 0; k < 2; ++k) {
        const int c = tid + k * 256;
        const float* __restrict__ w2row = w2base + c * NHID;
        float z = 0.f;
#pragma unroll
        for (int hh = 0; hh < NHID; ++hh) z += hs[hh] * w2row[hh];
        gate[b * NC + c] = 1.0f / (1.0f + expf(-z));
    }
}

// ---------------- Kernel 3: out = x * gate[b,c] ----------------
// Two planes per block, DESCENDING plane order (harvest L3 tail of pool's
// read). Gate loads are wave-uniform (scalar). Non-temporal stores so the
// 512 MiB output stream does not evict x from the Infinity Cache.
__global__ __launch_bounds__(256) void scale_kernel(const float* __restrict__ x,
                                                    const float* __restrict__ gate,
                                                    float* __restrict__ out) {
    const int pair = (NPLANES / 2 - 1) - blockIdx.x;     // descending
    const int p0 = pair * 2;
    const float g0 = gate[p0];
    const float g1 = gate[p0 + 1];
    const size_t base = (size_t)pair * 2048;             // in float4 units
    const f32x4* __restrict__ xin = reinterpret_cast<const f32x4*>(x);
    f32x4* __restrict__ o4 = reinterpret_cast<f32x4*>(out);
    const int t = threadIdx.x;

#pragma unroll
    for (int k = 0; k < 4; ++k) {
        const size_t i = base + (size_t)k * 256 + t;
        f32x4 v = xin[i];
        v *= g0;
        __builtin_nontemporal_store(v, &o4[i]);
    }
#pragma unroll
    for (int k = 0; k < 4; ++k) {
        const size_t i = base + 1024 + (size_t)k * 256 + t;
        f32x4 v = xin[i];
        v *= g1;
        __builtin_nontemporal_store(v, &o4[i]);
    }
}

extern "C" void kernel_launch(void* const* d_in, const int* in_sizes, int n_in,
                              void* d_out, int out_size, void* d_ws, size_t ws_size,
                              hipStream_t stream) {
    const float* x       = (const float*)d_in[0];
    const int*   dataset = (const int*)d_in[1];
    const float* W1      = (const float*)d_in[2];
    const float* W2      = (const float*)d_in[3];
    float* out = (float*)d_out;

    float* y    = (float*)d_ws;          // NB*NC floats
    float* gate = y + NB * NC;           // NB*NC floats

    pool_kernel<<<NPLANES / 4, 256, 0, stream>>>(x, y);
    gate_kernel<<<NB, 256, 0, stream>>>(y, dataset, W1, W2, gate);
    scale_kernel<<<NPLANES / 2, 256, 0, stream>>>(x, gate, out);
}

// Round 3
// 283.631 us; speedup vs baseline: 1.2459x; 1.0045x over previous
//
#include <hip/hip_runtime.h>
#include <math.h>

#define NB 64
#define NC 512
#define NHW 4096
#define NHID 32
#define NPLANES (NB * NC)          // 32768 planes of 4096 floats

typedef float f32x4 __attribute__((ext_vector_type(4)));

// ---------------- Kernel 1: global average pool ----------------
// Wave-per-plane. Ascending plane order. First half of x is loaded with
// non-temporal hint (streaming, don't allocate L3); second half loads
// normally so the tail 256 MiB is L3-resident when scale starts.
__global__ __launch_bounds__(256) void pool_kernel(const float* __restrict__ x,
                                                   float* __restrict__ y) {
    const int wid   = threadIdx.x >> 6;
    const int lane  = threadIdx.x & 63;
    const int plane = blockIdx.x * 4 + wid;
    const f32x4* __restrict__ xin =
        reinterpret_cast<const f32x4*>(x + (size_t)plane * NHW);

    float s = 0.f;
    if (plane < NPLANES / 2) {
#pragma unroll
        for (int i = 0; i < 16; ++i) {
            f32x4 v = __builtin_nontemporal_load(&xin[lane + i * 64]);
            s += v.x + v.y + v.z + v.w;
        }
    } else {
#pragma unroll
        for (int i = 0; i < 16; ++i) {
            f32x4 v = xin[lane + i * 64];
            s += v.x + v.y + v.z + v.w;
        }
    }
#pragma unroll
    for (int o = 32; o; o >>= 1) s += __shfl_down(s, o, 64);
    if (lane == 0) y[plane] = s * (1.0f / NHW);
}

// ---------------- Kernel 2: routed 2-layer MLP -> sigmoid gate ----------------
__global__ __launch_bounds__(256) void gate_kernel(const float* __restrict__ y,
                                                   const int* __restrict__ dataset,
                                                   const float* __restrict__ W1,
                                                   const float* __restrict__ W2,
                                                   float* __restrict__ gate) {
    const int b = blockIdx.x;
    const int tid = threadIdx.x;

    __shared__ float ys[NC];
    __shared__ float hs[NHID];

    ys[tid]       = y[b * NC + tid];
    ys[tid + 256] = y[b * NC + tid + 256];
    const int e = dataset[b];
    __syncthreads();

    const int hid = tid >> 3;
    const int j   = tid & 7;
    const float* __restrict__ w1row = W1 + ((size_t)e * NHID + hid) * NC;
    float acc = 0.f;
    for (int c = j; c < NC; c += 8) acc += ys[c] * w1row[c];
#pragma unroll
    for (int o = 4; o; o >>= 1) acc += __shfl_down(acc, o, 8);
    if (j == 0) hs[hid] = fmaxf(acc, 0.f);
    __syncthreads();

    const float* __restrict__ w2base = W2 + (size_t)e * NC * NHID;
#pragma unroll
    for (int k = 0; k < 2; ++k) {
        const int c = tid + k * 256;
        const float* __restrict__ w2row = w2base + c * NHID;
        float z = 0.f;
#pragma unroll
        for (int hh = 0; hh < NHID; ++hh) z += hs[hh] * w2row[hh];
        gate[b * NC + c] = 1.0f / (1.0f + expf(-z));
    }
}

// ---------------- Kernel 3: out = x * gate[b,c] ----------------
// Descending plane order. Tail half reads normal (harvest pool's L3
// residue); head half reads nt (pure stream). All stores nt so the output
// stream never evicts x from the Infinity Cache.
__global__ __launch_bounds__(256) void scale_kernel(const float* __restrict__ x,
                                                    const float* __restrict__ gate,
                                                    float* __restrict__ out) {
    const int pair = (NPLANES / 2 - 1) - blockIdx.x;     // descending
    const int p0 = pair * 2;
    const float g0 = gate[p0];
    const float g1 = gate[p0 + 1];
    const size_t base = (size_t)pair * 2048;             // float4 units
    const f32x4* __restrict__ xin = reinterpret_cast<const f32x4*>(x);
    f32x4* __restrict__ o4 = reinterpret_cast<f32x4*>(out);
    const int t = threadIdx.x;

    if (p0 >= NPLANES / 2) {                             // tail half: expect L3 hits
#pragma unroll
        for (int k = 0; k < 4; ++k) {
            const size_t i = base + (size_t)k * 256 + t;
            f32x4 v = xin[i];
            v *= g0;
            __builtin_nontemporal_store(v, &o4[i]);
        }
#pragma unroll
        for (int k = 0; k < 4; ++k) {
            const size_t i = base + 1024 + (size_t)k * 256 + t;
            f32x4 v = xin[i];
            v *= g1;
            __builtin_nontemporal_store(v, &o4[i]);
        }
    } else {                                             // head half: pure stream
#pragma unroll
        for (int k = 0; k < 4; ++k) {
            const size_t i = base + (size_t)k * 256 + t;
            f32x4 v = __builtin_nontemporal_load(&xin[i]);
            v *= g0;
            __builtin_nontemporal_store(v, &o4[i]);
        }
#pragma unroll
        for (int k = 0; k < 4; ++k) {
            const size_t i = base + 1024 + (size_t)k * 256 + t;
            f32x4 v = __builtin_nontemporal_load(&xin[i]);
            v *= g1;
            __builtin_nontemporal_store(v, &o4[i]);
        }
    }
}

extern "C" void kernel_launch(void* const* d_in, const int* in_sizes, int n_in,
                              void* d_out, int out_size, void* d_ws, size_t ws_size,
                              hipStream_t stream) {
    const float* x       = (const float*)d_in[0];
    const int*   dataset = (const int*)d_in[1];
    const float* W1      = (const float*)d_in[2];
    const float* W2      = (const float*)d_in[3];
    float* out = (float*)d_out;

    float* y    = (float*)d_ws;          // NB*NC floats
    float* gate = y + NB * NC;           // NB*NC floats

    pool_kernel<<<NPLANES / 4, 256, 0, stream>>>(x, y);
    gate_kernel<<<NB, 256, 0, stream>>>(y, dataset, W1, W2, gate);
    scale_kernel<<<NPLANES / 2, 256, 0, stream>>>(x, gate, out);
}